// Round 4
// baseline (596.323 us; speedup 1.0000x reference)
//
#include <hip/hip_runtime.h>
#include <math.h>

namespace {
constexpr int N = 1000000;
constexpr int E = 1000000;
constexpr int C = 64;            // poss_node cols; poss_edge has C+1 = 65 cols
constexpr int NODE_BLOCKS = 1024;   // ws layout proven in R1/R3: 2*1024 + 4*2048 floats = 40960 B
constexpr int EDGE_BLOCKS = 2048;
constexpr int BLOCK = 256;
constexpr int GROUPS_PER_BLOCK = BLOCK / 16;                  // 16 groups of 16 lanes
constexpr int TOTAL_GROUPS = EDGE_BLOCKS * GROUPS_PER_BLOCK;  // 32768
constexpr int NODE_STRIDE = NODE_BLOCKS * BLOCK;              // 262144
constexpr int NODE_ITERS = (N + NODE_STRIDE - 1) / NODE_STRIDE; // 4
constexpr double SEMI_LAMBDA = 0.5;
constexpr double EDGE_LAMBDA = 1.0;
}

__device__ __forceinline__ float waveReduceSum(float v) {
#pragma unroll
    for (int off = 32; off > 0; off >>= 1) v += __shfl_down(v, off, 64);
    return v;
}

// 16B load from a pointer that is only guaranteed 4B-aligned (rows have 260B stride).
// __builtin_memcpy -> load <4 x float>, align 4 -> global_load_dwordx4 (gfx950 unaligned mode).
__device__ __forceinline__ float4 ld4(const float* __restrict__ p) {
    float4 v;
    __builtin_memcpy(&v, p, sizeof(float4));
    return v;
}

// ---------------- node loss: -sum(mask * log p[i, gt[i]]) / sum(mask) ----------
// All 4 grid-stride iterations batched: mask/gt loads issue together, then all
// 4 gathers issue together (independent -> 4x memory-level parallelism).
__global__ __launch_bounds__(BLOCK) void node_kernel(
    const float* __restrict__ poss_node,
    const int* __restrict__ gt,
    const int* __restrict__ mask,
    float* __restrict__ partials)   // [2][NODE_BLOCKS]
{
    const int i0 = blockIdx.x * BLOCK + threadIdx.x;

    bool act[NODE_ITERS];
    int  g[NODE_ITERS];
#pragma unroll
    for (int j = 0; j < NODE_ITERS; ++j) {
        const int idx = i0 + j * NODE_STRIDE;
        const bool v = idx < N;
        const int m  = v ? mask[idx] : 0;
        g[j]   = v ? gt[idx] : 0;
        act[j] = v && (m != 0);
    }

    float p[NODE_ITERS];
#pragma unroll
    for (int j = 0; j < NODE_ITERS; ++j) {
        const size_t off = act[j] ? ((size_t)(i0 + j * NODE_STRIDE) * C + g[j]) : 0;
        p[j] = poss_node[off];          // masked-out lanes hit element 0 (cached)
    }

    float lsum = 0.f, cnt = 0.f;
#pragma unroll
    for (int j = 0; j < NODE_ITERS; ++j) {
        if (act[j]) { lsum += logf(p[j]); cnt += 1.f; }
    }

    __shared__ float s0[BLOCK / 64], s1[BLOCK / 64];
    lsum = waveReduceSum(lsum);
    cnt  = waveReduceSum(cnt);
    const int lane = threadIdx.x & 63, wv = threadIdx.x >> 6;
    if (lane == 0) { s0[wv] = lsum; s1[wv] = cnt; }
    __syncthreads();
    if (threadIdx.x == 0) {
        float a = 0.f, b = 0.f;
#pragma unroll
        for (int w = 0; w < BLOCK / 64; ++w) { a += s0[w]; b += s1[w]; }
        partials[blockIdx.x]               = a;
        partials[NODE_BLOCKS + blockIdx.x] = b;
    }
}

// ---------------- edge: 16-lane group per edge, dwordx4 row reads --------------
__global__ __launch_bounds__(BLOCK) void edge_kernel(
    const float* __restrict__ poss_edge,
    const int* __restrict__ gt,
    const int* __restrict__ mask,
    const int* __restrict__ edges,
    float* __restrict__ partials)   // [4][EDGE_BLOCKS]: s1, sqdiff, pos_logs, label_cnt
{
    const int t   = threadIdx.x & 15;                       // sub-lane in group
    const int grp = threadIdx.x >> 4;                       // group in block
    const int globalGroup = blockIdx.x * GROUPS_PER_BLOCK + grp;

    float s1 = 0.f, sq = 0.f, pos = 0.f, lcnt = 0.f;

    for (int e = globalGroup; e < E; e += TOTAL_GROUPS) {
        const int2 ep = *(const int2*)(edges + 2 * (size_t)e);
        const int e0 = ep.x, e1 = ep.y;

        const float* __restrict__ ra = poss_edge + (size_t)e0 * (C + 1);
        const float* __restrict__ rb = poss_edge + (size_t)e1 * (C + 1);
        const float* __restrict__ re = poss_edge + (size_t)e  * (C + 1);

        // ---- issue ALL loads up front (independent; only dependence is edges->rows)
        const float4 av = ld4(ra + 4 * t);     // group covers cols 0..63, 256B/instr
        const float4 bv = ld4(rb + 4 * t);
        const float ra64 = ra[C];              // broadcast
        const float rb64 = rb[C];
        const float p_last = re[C];
        const int m0i = mask[e0];
        const int m1i = mask[e1];
        const int g0  = gt[e0];
        const int g1  = gt[e1];
        const float pg0 = re[g0];              // unconditional: overlaps latency
        const float pg1 = re[g1];

        // ---- sqdiff
        const float d0 = av.x - bv.x, d1 = av.y - bv.y,
                    d2 = av.z - bv.z, d3 = av.w - bv.w;
        float acc = fmaf(d0, d0, fmaf(d1, d1, fmaf(d2, d2, d3 * d3)));
        const float dl = ra64 - rb64;
        if (t == 0) acc = fmaf(dl, dl, acc);
        sq += acc;

        // ---- label terms (group-uniform values; only lane 0 accumulates)
        const bool b0 = (m0i != 0), b1 = (m1i != 0);
        float contrib = 0.f;
        if (b0 & b1) contrib = (g0 == g1) ? logf(pg0) : logf(p_last);
        else if (b0) contrib = logf(p_last + pg0);
        else if (b1) contrib = logf(p_last + pg1);
        if (t == 0) {
            s1 += 1.f - p_last;
            pos += contrib;
            lcnt += (b0 | b1) ? 1.f : 0.f;
        }
    }

    __shared__ float s[4][BLOCK / 64];
    s1   = waveReduceSum(s1);
    sq   = waveReduceSum(sq);
    pos  = waveReduceSum(pos);
    lcnt = waveReduceSum(lcnt);
    const int lane = threadIdx.x & 63, wv = threadIdx.x >> 6;
    if (lane == 0) { s[0][wv] = s1; s[1][wv] = sq; s[2][wv] = pos; s[3][wv] = lcnt; }
    __syncthreads();
    if (threadIdx.x == 0) {
        float a = 0.f, b = 0.f, c = 0.f, d = 0.f;
#pragma unroll
        for (int w = 0; w < BLOCK / 64; ++w) {
            a += s[0][w]; b += s[1][w]; c += s[2][w]; d += s[3][w];
        }
        partials[0 * EDGE_BLOCKS + blockIdx.x] = a;
        partials[1 * EDGE_BLOCKS + blockIdx.x] = b;
        partials[2 * EDGE_BLOCKS + blockIdx.x] = c;
        partials[3 * EDGE_BLOCKS + blockIdx.x] = d;
    }
}

// ---------------- final combine in fp64 ----------------------------------------
__global__ __launch_bounds__(BLOCK) void finalize_kernel(
    const float* __restrict__ node_partials,
    const float* __restrict__ edge_partials,
    float* __restrict__ out)
{
    double a0 = 0, a1 = 0, a2 = 0, a3 = 0, a4 = 0, a5 = 0;
    for (int i = threadIdx.x; i < NODE_BLOCKS; i += BLOCK) {
        a0 += (double)node_partials[i];
        a1 += (double)node_partials[NODE_BLOCKS + i];
    }
    for (int i = threadIdx.x; i < EDGE_BLOCKS; i += BLOCK) {
        a2 += (double)edge_partials[0 * EDGE_BLOCKS + i];
        a3 += (double)edge_partials[1 * EDGE_BLOCKS + i];
        a4 += (double)edge_partials[2 * EDGE_BLOCKS + i];
        a5 += (double)edge_partials[3 * EDGE_BLOCKS + i];
    }
#pragma unroll
    for (int off = 32; off > 0; off >>= 1) {
        a0 += __shfl_down(a0, off, 64);
        a1 += __shfl_down(a1, off, 64);
        a2 += __shfl_down(a2, off, 64);
        a3 += __shfl_down(a3, off, 64);
        a4 += __shfl_down(a4, off, 64);
        a5 += __shfl_down(a5, off, 64);
    }
    __shared__ double sd[6][BLOCK / 64];
    const int lane = threadIdx.x & 63, wv = threadIdx.x >> 6;
    if (lane == 0) {
        sd[0][wv] = a0; sd[1][wv] = a1; sd[2][wv] = a2;
        sd[3][wv] = a3; sd[4][wv] = a4; sd[5][wv] = a5;
    }
    __syncthreads();
    if (threadIdx.x == 0) {
        double t[6];
#pragma unroll
        for (int k = 0; k < 6; ++k) {
            double v = 0;
#pragma unroll
            for (int w = 0; w < BLOCK / 64; ++w) v += sd[k][w];
            t[k] = v;
        }
        const double logp_sum  = t[0];
        const double mask_cnt  = t[1];
        const double s1_sum    = t[2];
        const double sq_sum    = t[3];
        const double pos_sum   = t[4];
        const double label_cnt = t[5];

        const double loss      = -logp_sum / mask_cnt;
        const double semi      = SEMI_LAMBDA * s1_sum * sq_sum;
        const double raw       = -pos_sum;
        const double edge_loss = raw * (EDGE_LAMBDA * EDGE_LAMBDA) / (label_cnt * label_cnt);

        out[0] = (float)(loss + semi + edge_loss);
    }
}

extern "C" void kernel_launch(void* const* d_in, const int* in_sizes, int n_in,
                              void* d_out, int out_size, void* d_ws, size_t ws_size,
                              hipStream_t stream) {
    const float* poss_node = (const float*)d_in[0];
    const float* poss_edge = (const float*)d_in[1];
    const int*   gt        = (const int*)d_in[2];
    const int*   mask      = (const int*)d_in[3];
    const int*   edges     = (const int*)d_in[4];
    float*       out       = (float*)d_out;

    float* node_partials = (float*)d_ws;                         // 2 * NODE_BLOCKS floats
    float* edge_partials = node_partials + 2 * NODE_BLOCKS;      // 4 * EDGE_BLOCKS floats

    node_kernel<<<NODE_BLOCKS, BLOCK, 0, stream>>>(poss_node, gt, mask, node_partials);
    edge_kernel<<<EDGE_BLOCKS, BLOCK, 0, stream>>>(poss_edge, gt, mask, edges, edge_partials);
    finalize_kernel<<<1, BLOCK, 0, stream>>>(node_partials, edge_partials, out);
}

// Round 5
// 589.088 us; speedup vs baseline: 1.0123x; 1.0123x over previous
//
#include <hip/hip_runtime.h>
#include <math.h>

namespace {
constexpr int N = 1000000;
constexpr int E = 1000000;
constexpr int C = 64;            // poss_node cols; poss_edge has C+1 = 65 cols
constexpr int NODE_BLOCKS = 1024;   // ws layout proven in R1/R3: 2*1024 + 4*2048 floats = 40960 B
constexpr int EDGE_BLOCKS = 2048;
constexpr int BLOCK = 256;
constexpr int GROUPS_PER_BLOCK = BLOCK / 16;                  // 16 groups of 16 lanes
constexpr int TOTAL_GROUPS = EDGE_BLOCKS * GROUPS_PER_BLOCK;  // 32768
constexpr int NODE_STRIDE = NODE_BLOCKS * BLOCK;              // 262144
constexpr int NODE_ITERS = (N + NODE_STRIDE - 1) / NODE_STRIDE; // 4
constexpr double SEMI_LAMBDA = 0.5;
constexpr double EDGE_LAMBDA = 1.0;
}

__device__ __forceinline__ float waveReduceSum(float v) {
#pragma unroll
    for (int off = 32; off > 0; off >>= 1) v += __shfl_down(v, off, 64);
    return v;
}

// 16B load from a pointer that is only guaranteed 4B-aligned (rows have 260B stride).
__device__ __forceinline__ float4 ld4(const float* __restrict__ p) {
    float4 v;
    __builtin_memcpy(&v, p, sizeof(float4));
    return v;
}

// ---------------- node loss: -sum(mask * log p[i, gt[i]]) / sum(mask) ----------
__global__ __launch_bounds__(BLOCK) void node_kernel(
    const float* __restrict__ poss_node,
    const int* __restrict__ gt,
    const int* __restrict__ mask,
    float* __restrict__ partials)   // [2][NODE_BLOCKS]
{
    const int i0 = blockIdx.x * BLOCK + threadIdx.x;

    bool act[NODE_ITERS];
    int  g[NODE_ITERS];
#pragma unroll
    for (int j = 0; j < NODE_ITERS; ++j) {
        const int idx = i0 + j * NODE_STRIDE;
        const bool v = idx < N;
        const int m  = v ? mask[idx] : 0;
        g[j]   = v ? gt[idx] : 0;
        act[j] = v && (m != 0);
    }

    float p[NODE_ITERS];
#pragma unroll
    for (int j = 0; j < NODE_ITERS; ++j) {
        const size_t off = act[j] ? ((size_t)(i0 + j * NODE_STRIDE) * C + g[j]) : 0;
        p[j] = poss_node[off];          // masked-out lanes hit element 0 (cached)
    }

    float lsum = 0.f, cnt = 0.f;
#pragma unroll
    for (int j = 0; j < NODE_ITERS; ++j) {
        if (act[j]) { lsum += logf(p[j]); cnt += 1.f; }
    }

    __shared__ float s0[BLOCK / 64], s1[BLOCK / 64];
    lsum = waveReduceSum(lsum);
    cnt  = waveReduceSum(cnt);
    const int lane = threadIdx.x & 63, wv = threadIdx.x >> 6;
    if (lane == 0) { s0[wv] = lsum; s1[wv] = cnt; }
    __syncthreads();
    if (threadIdx.x == 0) {
        float a = 0.f, b = 0.f;
#pragma unroll
        for (int w = 0; w < BLOCK / 64; ++w) { a += s0[w]; b += s1[w]; }
        partials[blockIdx.x]               = a;
        partials[NODE_BLOCKS + blockIdx.x] = b;
    }
}

// ---------------- edge: 16-lane group per edge, 2-edge unroll for MLP ----------
__global__ __launch_bounds__(BLOCK) void edge_kernel(
    const float* __restrict__ poss_edge,
    const int* __restrict__ gt,
    const int* __restrict__ mask,
    const int* __restrict__ edges,
    float* __restrict__ partials)   // [4][EDGE_BLOCKS]: s1, sqdiff, pos_logs, label_cnt
{
    const int t   = threadIdx.x & 15;
    const int grp = threadIdx.x >> 4;
    const int globalGroup = blockIdx.x * GROUPS_PER_BLOCK + grp;

    float s1 = 0.f, sq = 0.f, pos = 0.f, lcnt = 0.f;

    for (int e = globalGroup; e < E; e += 2 * TOTAL_GROUPS) {
        const int eB = e + TOTAL_GROUPS;
        const bool have2 = eB < E;

        // ---- edge-index loads for both edges, up front
        const int2 epA = *(const int2*)(edges + 2 * (size_t)e);
        const int2 epB = have2 ? *(const int2*)(edges + 2 * (size_t)eB) : make_int2(0, 0);
        const int a0i = epA.x, a1i = epA.y;
        const int b0i = epB.x, b1i = epB.y;

        const float* __restrict__ raA = poss_edge + (size_t)a0i * (C + 1);
        const float* __restrict__ rbA = poss_edge + (size_t)a1i * (C + 1);
        const float* __restrict__ reA = poss_edge + (size_t)e   * (C + 1);
        const float* __restrict__ raB = poss_edge + (size_t)b0i * (C + 1);
        const float* __restrict__ rbB = poss_edge + (size_t)b1i * (C + 1);
        const float* __restrict__ reB = poss_edge + (size_t)(have2 ? eB : 0) * (C + 1);

        // ---- all four heavy row loads issued back-to-back (64B/lane in flight)
        const float4 avA = ld4(raA + 4 * t);
        const float4 bvA = ld4(rbA + 4 * t);
        const float4 avB = ld4(raB + 4 * t);
        const float4 bvB = ld4(rbB + 4 * t);

        // ---- light broadcast loads
        const float raA64 = raA[C], rbA64 = rbA[C], pLA = reA[C];
        const float raB64 = raB[C], rbB64 = rbB[C], pLB = reB[C];
        const int mA0 = mask[a0i], mA1 = mask[a1i];
        const int mB0 = mask[b0i], mB1 = mask[b1i];

        // ---- sqdiff A
        {
            const float d0 = avA.x - bvA.x, d1 = avA.y - bvA.y,
                        d2 = avA.z - bvA.z, d3 = avA.w - bvA.w;
            float acc = fmaf(d0, d0, fmaf(d1, d1, fmaf(d2, d2, d3 * d3)));
            const float dl = raA64 - rbA64;
            if (t == 0) acc = fmaf(dl, dl, acc);
            sq += acc;
        }
        // ---- sqdiff B (gated)
        if (have2) {
            const float d0 = avB.x - bvB.x, d1 = avB.y - bvB.y,
                        d2 = avB.z - bvB.z, d3 = avB.w - bvB.w;
            float acc = fmaf(d0, d0, fmaf(d1, d1, fmaf(d2, d2, d3 * d3)));
            const float dl = raB64 - rbB64;
            if (t == 0) acc = fmaf(dl, dl, acc);
            sq += acc;
        }

        // ---- label terms A (conditional loads — saves ~50MB vs unconditional)
        {
            const bool m0 = (mA0 != 0), m1 = (mA1 != 0);
            if (m0 | m1) {
                const int g0 = gt[a0i], g1 = gt[a1i];
                float contrib;
                if (m0 & m1) contrib = (g0 == g1) ? logf(reA[g0]) : logf(pLA);
                else if (m0) contrib = logf(pLA + reA[g0]);
                else         contrib = logf(pLA + reA[g1]);
                if (t == 0) { pos += contrib; lcnt += 1.f; }
            }
            if (t == 0) s1 += 1.f - pLA;
        }
        // ---- label terms B (gated)
        if (have2) {
            const bool m0 = (mB0 != 0), m1 = (mB1 != 0);
            if (m0 | m1) {
                const int g0 = gt[b0i], g1 = gt[b1i];
                float contrib;
                if (m0 & m1) contrib = (g0 == g1) ? logf(reB[g0]) : logf(pLB);
                else if (m0) contrib = logf(pLB + reB[g0]);
                else         contrib = logf(pLB + reB[g1]);
                if (t == 0) { pos += contrib; lcnt += 1.f; }
            }
            if (t == 0) s1 += 1.f - pLB;
        }
    }

    __shared__ float s[4][BLOCK / 64];
    s1   = waveReduceSum(s1);
    sq   = waveReduceSum(sq);
    pos  = waveReduceSum(pos);
    lcnt = waveReduceSum(lcnt);
    const int lane = threadIdx.x & 63, wv = threadIdx.x >> 6;
    if (lane == 0) { s[0][wv] = s1; s[1][wv] = sq; s[2][wv] = pos; s[3][wv] = lcnt; }
    __syncthreads();
    if (threadIdx.x == 0) {
        float a = 0.f, b = 0.f, c = 0.f, d = 0.f;
#pragma unroll
        for (int w = 0; w < BLOCK / 64; ++w) {
            a += s[0][w]; b += s[1][w]; c += s[2][w]; d += s[3][w];
        }
        partials[0 * EDGE_BLOCKS + blockIdx.x] = a;
        partials[1 * EDGE_BLOCKS + blockIdx.x] = b;
        partials[2 * EDGE_BLOCKS + blockIdx.x] = c;
        partials[3 * EDGE_BLOCKS + blockIdx.x] = d;
    }
}

// ---------------- final combine in fp64 ----------------------------------------
__global__ __launch_bounds__(BLOCK) void finalize_kernel(
    const float* __restrict__ node_partials,
    const float* __restrict__ edge_partials,
    float* __restrict__ out)
{
    double a0 = 0, a1 = 0, a2 = 0, a3 = 0, a4 = 0, a5 = 0;
    for (int i = threadIdx.x; i < NODE_BLOCKS; i += BLOCK) {
        a0 += (double)node_partials[i];
        a1 += (double)node_partials[NODE_BLOCKS + i];
    }
    for (int i = threadIdx.x; i < EDGE_BLOCKS; i += BLOCK) {
        a2 += (double)edge_partials[0 * EDGE_BLOCKS + i];
        a3 += (double)edge_partials[1 * EDGE_BLOCKS + i];
        a4 += (double)edge_partials[2 * EDGE_BLOCKS + i];
        a5 += (double)edge_partials[3 * EDGE_BLOCKS + i];
    }
#pragma unroll
    for (int off = 32; off > 0; off >>= 1) {
        a0 += __shfl_down(a0, off, 64);
        a1 += __shfl_down(a1, off, 64);
        a2 += __shfl_down(a2, off, 64);
        a3 += __shfl_down(a3, off, 64);
        a4 += __shfl_down(a4, off, 64);
        a5 += __shfl_down(a5, off, 64);
    }
    __shared__ double sd[6][BLOCK / 64];
    const int lane = threadIdx.x & 63, wv = threadIdx.x >> 6;
    if (lane == 0) {
        sd[0][wv] = a0; sd[1][wv] = a1; sd[2][wv] = a2;
        sd[3][wv] = a3; sd[4][wv] = a4; sd[5][wv] = a5;
    }
    __syncthreads();
    if (threadIdx.x == 0) {
        double t[6];
#pragma unroll
        for (int k = 0; k < 6; ++k) {
            double v = 0;
#pragma unroll
            for (int w = 0; w < BLOCK / 64; ++w) v += sd[k][w];
            t[k] = v;
        }
        const double logp_sum  = t[0];
        const double mask_cnt  = t[1];
        const double s1_sum    = t[2];
        const double sq_sum    = t[3];
        const double pos_sum   = t[4];
        const double label_cnt = t[5];

        const double loss      = -logp_sum / mask_cnt;
        const double semi      = SEMI_LAMBDA * s1_sum * sq_sum;
        const double raw       = -pos_sum;
        const double edge_loss = raw * (EDGE_LAMBDA * EDGE_LAMBDA) / (label_cnt * label_cnt);

        out[0] = (float)(loss + semi + edge_loss);
    }
}

extern "C" void kernel_launch(void* const* d_in, const int* in_sizes, int n_in,
                              void* d_out, int out_size, void* d_ws, size_t ws_size,
                              hipStream_t stream) {
    const float* poss_node = (const float*)d_in[0];
    const float* poss_edge = (const float*)d_in[1];
    const int*   gt        = (const int*)d_in[2];
    const int*   mask      = (const int*)d_in[3];
    const int*   edges     = (const int*)d_in[4];
    float*       out       = (float*)d_out;

    float* node_partials = (float*)d_ws;                         // 2 * NODE_BLOCKS floats
    float* edge_partials = node_partials + 2 * NODE_BLOCKS;      // 4 * EDGE_BLOCKS floats

    node_kernel<<<NODE_BLOCKS, BLOCK, 0, stream>>>(poss_node, gt, mask, node_partials);
    edge_kernel<<<EDGE_BLOCKS, BLOCK, 0, stream>>>(poss_edge, gt, mask, edges, edge_partials);
    finalize_kernel<<<1, BLOCK, 0, stream>>>(node_partials, edge_partials, out);
}